// Round 19
// baseline (104.865 us; speedup 1.0000x reference)
//
#include <hip/hip_runtime.h>
#include <math.h>

typedef __bf16 bf16;
typedef __bf16 bf16x8 __attribute__((ext_vector_type(8)));
typedef __bf16 bf16x4 __attribute__((ext_vector_type(4)));
typedef __bf16 bf16x2 __attribute__((ext_vector_type(2)));
typedef float  f32x4  __attribute__((ext_vector_type(4)));

#define B_DIM 2
#define T_LEN 2048
#define D_DIM 1024
#define N_HEAD 16
#define HEAD_D 64
#define M_ROWS (B_DIM * T_LEN)  // 4096
#define QSCALE 0.18033688011112042f   // 0.125 * log2(e): exp2-domain softmax

#define GLDS16(g, l)                                                          \
    __builtin_amdgcn_global_load_lds(                                         \
        (const __attribute__((address_space(1))) void*)(g),                   \
        (__attribute__((address_space(3))) void*)(l), 16, 0, 0)

// ---------------- fused f32 -> bf16 conversion of x + all weights ---------
// grid-stride x4: 2048 blocks, 4 float4 per thread (ILP for the BW-bound pass)
__global__ void prep_cvt(const float* __restrict__ x, const float* __restrict__ wq,
                         const float* __restrict__ wk, const float* __restrict__ wv,
                         const float* __restrict__ wo, bf16* __restrict__ xb,
                         bf16* __restrict__ wqkv, bf16* __restrict__ wob) {
    const int id0 = blockIdx.x * blockDim.x + threadIdx.x;   // 0..524287
#pragma unroll
    for (int u = 0; u < 4; ++u) {
        int id = id0 + u * (1 << 19);                         // float4 units
        const float* src; bf16* dst; int off;
        if (id < (1 << 20)) { src = x; dst = xb; off = id; }
        else {
            int r = id - (1 << 20);
            int wi = r >> 18;
            off = r & ((1 << 18) - 1);
            src = wi == 0 ? wq : wi == 1 ? wk : wi == 2 ? wv : wo;
            dst = wi < 3 ? wqkv + ((size_t)wi << 20) : wob;
        }
        float4 v = reinterpret_cast<const float4*>(src)[off];
        bf16x4 w;
        w[0] = (bf16)v.x; w[1] = (bf16)v.y; w[2] = (bf16)v.z; w[3] = (bf16)v.w;
        reinterpret_cast<bf16x4*>(dst)[off] = w;
    }
}

// ---------------- GEMM: C = A[M,K] * Bm[N,K]^T ----------------------------
// m97 structure: single-buffered 32KB LDS, global_load_lds w16, src-side XOR
// swizzle, (256,4) — measured best; (256,5) was neutral-to-worse (R17).
// MODE 0: N=3072 fused QKV -> q plain head-major [B,H,T,hd];
// k head-major WITH ROPE fused in epilogue; v transposed [B,H,hd,T].
// MODE 1: N=1024 -> f32 row-major [M,N].
template <int MODE>
__global__ __launch_bounds__(256, 4)
void gemm_glds(const bf16* __restrict__ A, const bf16* __restrict__ Bm,
               bf16* __restrict__ q, bf16* __restrict__ k, bf16* __restrict__ v,
               float* __restrict__ outf, const float* __restrict__ fc,
               const float* __restrict__ fs) {
    constexpr int K = D_DIM;
    __shared__ bf16 As[128 * 64];
    __shared__ bf16 Bs[128 * 64];
    const int tid = threadIdx.x, lane = tid & 63, wave = tid >> 6;
    const int wr = wave >> 1, wc = wave & 1;
    const int rowg = lane >> 4, col0 = lane & 15;

    const int nwg = gridDim.x * gridDim.y, cpx = nwg >> 3;
    const int lin = blockIdx.x + blockIdx.y * gridDim.x;
    const int nid = (lin & 7) * cpx + (lin >> 3);
    const int bx = nid % gridDim.x, by = nid / gridDim.x;
    const int m0 = by * 128, n0 = bx * 128;

    const int srow = lane >> 3;
    const int schk = (lane & 7) ^ srow;
    const bf16* gA = A + (size_t)(m0 + wave * 32 + srow) * K + schk * 8;
    const bf16* gB = Bm + (size_t)(n0 + wave * 32 + srow) * K + schk * 8;

    f32x4 acc[4][4];
    f32x4 zero = {0.f, 0.f, 0.f, 0.f};
#pragma unroll
    for (int i = 0; i < 4; i++)
#pragma unroll
        for (int j = 0; j < 4; j++) acc[i][j] = zero;

#pragma unroll 1
    for (int kt = 0; kt < 16; ++kt) {
        const int k0 = kt * 64;
#pragma unroll
        for (int t = 0; t < 4; ++t) {
            GLDS16(gA + k0 + t * 8 * K, &As[(wave * 32 + t * 8) * 64]);
            GLDS16(gB + k0 + t * 8 * K, &Bs[(wave * 32 + t * 8) * 64]);
        }
        __syncthreads();
#pragma unroll
        for (int kk = 0; kk < 2; ++kk) {
            bf16x8 af[4], bfr[4];
#pragma unroll
            for (int i = 0; i < 4; i++) {
                int R = wr * 64 + i * 16 + col0;
                af[i] = *reinterpret_cast<const bf16x8*>(&As[R * 64 + (((kk * 4 + rowg) ^ (R & 7)) * 8)]);
            }
#pragma unroll
            for (int j = 0; j < 4; j++) {
                int R = wc * 64 + j * 16 + col0;
                bfr[j] = *reinterpret_cast<const bf16x8*>(&Bs[R * 64 + (((kk * 4 + rowg) ^ (R & 7)) * 8)]);
            }
#pragma unroll
            for (int i = 0; i < 4; i++)
#pragma unroll
                for (int j = 0; j < 4; j++)
                    acc[i][j] = __builtin_amdgcn_mfma_f32_16x16x32_bf16(af[i], bfr[j], acc[i][j], 0, 0, 0);
        }
        __syncthreads();
    }

    if constexpr (MODE == 0) {
        const int which = bx >> 3;                    // 0=q, 1=k, 2=v
        if (which == 0) {                             // q: plain (attn ropes it)
#pragma unroll
            for (int i = 0; i < 4; i++)
#pragma unroll
                for (int j = 0; j < 4; j++)
#pragma unroll
                    for (int r = 0; r < 4; r++) {
                        int m = m0 + wr * 64 + i * 16 + rowg * 4 + r;
                        int n = (n0 + wc * 64 + j * 16 + col0) & 1023;
                        int b = m >> 11, t = m & 2047, h = n >> 6, d = n & 63;
                        q[(((size_t)(b * N_HEAD + h)) * T_LEN + t) * HEAD_D + d] = (bf16)acc[i][j][r];
                    }
        } else if (which == 1) {                      // k: rope fused (verified R10/R11)
            const float sgnf = (col0 & 1) ? 1.f : -1.f;
#pragma unroll
            for (int i = 0; i < 4; i++)
#pragma unroll
                for (int j = 0; j < 4; j++) {
                    int nn = (n0 + wc * 64 + j * 16 + col0) & 1023;
                    int h = nn >> 6, d = nn & 63, i2 = d >> 1;
#pragma unroll
                    for (int r = 0; r < 4; r++) {
                        int m = m0 + wr * 64 + i * 16 + rowg * 4 + r;
                        int b = m >> 11, t = m & 2047;
                        float own = acc[i][j][r];
                        float part = __shfl_xor(own, 1);
                        float c = fc[t * 32 + i2], s = fs[t * 32 + i2];
                        float res = own * c + part * (sgnf * s);   // rope pair
                        k[(((size_t)(b * N_HEAD + h)) * T_LEN + t) * HEAD_D + d] = (bf16)res;
                    }
                }
        } else {                                      // v: transposed
#pragma unroll
            for (int i = 0; i < 4; i++)
#pragma unroll
                for (int j = 0; j < 4; j++) {
                    bf16x4 pk;
#pragma unroll
                    for (int r = 0; r < 4; r++) pk[r] = (bf16)acc[i][j][r];
                    int m = m0 + wr * 64 + i * 16 + rowg * 4;
                    int n = (n0 + wc * 64 + j * 16 + col0) & 1023;
                    int b = m >> 11, t = m & 2047, h = n >> 6, d = n & 63;
                    *reinterpret_cast<bf16x4*>(
                        &v[(((size_t)(b * N_HEAD + h)) * HEAD_D + d) * T_LEN + t]) = pk;
                }
        }
    } else {
#pragma unroll
        for (int i = 0; i < 4; i++)
#pragma unroll
            for (int j = 0; j < 4; j++)
#pragma unroll
                for (int r = 0; r < 4; r++) {
                    int m = m0 + wr * 64 + i * 16 + rowg * 4 + r;
                    int n = n0 + wc * 64 + j * 16 + col0;
                    outf[(size_t)m * D_DIM + n] = acc[i][j][r];
                }
    }
}

// ---------------- rope helper: 8 bf16 = 4 (even,odd) pairs ----------------
__device__ inline bf16x8 rope8(bf16x8 v, f32x4 c4, f32x4 s4, float scale) {
    bf16x8 r;
#pragma unroll
    for (int m = 0; m < 4; ++m) {
        float a = (float)v[2 * m], b = (float)v[2 * m + 1];
        r[2 * m]     = (bf16)((a * c4[m] - b * s4[m]) * scale);
        r[2 * m + 1] = (bf16)((a * s4[m] + b * c4[m]) * scale);
    }
    return r;
}

// ---------------- causal flash attention (R12 config + exp2 domain) -------
// 4 waves x 16 q-rows = QBLK 64; KVBLK 64; double-buffered K/V LDS, one
// __syncthreads per tile, T14 reg-prefetch. Grid 1024, qi = 31 - (idx>>2)
// descending (LPT). bh pinned per XCD. Swapped QK^T and swapped PV
// (q = lane&15 everywhere). In-kernel Q-rope with 0.125*log2e -> softmax
// uses raw v_exp (exp2) with no per-element mul. Unconditional rescale,
// padded Ps[16][72]. Perturbations proven worse: shfl-P (+13µs), swizzled
// Ps (+1.4), (256,4) VGPR squeeze (+5.6), V-from-global (+42), GEMM
// (256,5) (+2.3).
__global__ __launch_bounds__(256, 3)
void attn_fwd(const bf16* __restrict__ qh, const bf16* __restrict__ kh,
              const bf16* __restrict__ vtg, const float* __restrict__ fc,
              const float* __restrict__ fs, bf16* __restrict__ ao) {
    __shared__ __align__(16) bf16 Ks[2][64 * 64];
    __shared__ __align__(16) bf16 Vs[2][64 * 64];
    __shared__ __align__(16) bf16 Ps[4][16][72];
    const int tid = threadIdx.x, lane = tid & 63, w = tid >> 6;
    const int g = lane >> 4, q15 = lane & 15;
    const int lin = blockIdx.x;                       // grid 1024
    const int xcd = lin & 7, idx = lin >> 3;
    const int qi = 31 - (idx >> 2);                   // descending -> LPT
    const int bh = xcd * 4 + (idx & 3);
    const size_t kbase = (size_t)bh * T_LEN * HEAD_D;   // [t][d]
    const size_t vbase = (size_t)bh * HEAD_D * T_LEN;   // [d][t]
    // staging: 256 threads x 2 rows per matrix (rows r and r+32)
    const int c0row = tid >> 3, ccg = tid & 7;
    const int swz = (ccg * 8) ^ ((c0row & 7) * 8);    // (c0row+32)&7 == c0row&7
    const int sel0 = c0row * 64 + swz;
    const int sel1 = sel0 + 32 * 64;
    const int ksw = (q15 & 7) * 8;

    const float NEGINF = -__builtin_inff();
    f32x4 zero = {0.f, 0.f, 0.f, 0.f};

    const int nt = qi + 1;
    const int qlo = qi * 64 + w * 16;

    // Q fragments: load, rope in-register, fold 0.125*log2(e) (exp2 domain)
    bf16x8 aq[2];
#pragma unroll
    for (int kk = 0; kk < 2; ++kk) {
        bf16x8 qv = *reinterpret_cast<const bf16x8*>(
            &qh[kbase + (size_t)(qlo + q15) * HEAD_D + kk * 32 + g * 8]);
        f32x4 c4 = *reinterpret_cast<const f32x4*>(&fc[(qlo + q15) * 32 + kk * 16 + g * 4]);
        f32x4 s4 = *reinterpret_cast<const f32x4*>(&fs[(qlo + q15) * 32 + kk * 16 + g * 4]);
        aq[kk] = rope8(qv, c4, s4, QSCALE);
    }

    f32x4 o[4];
#pragma unroll
    for (int j = 0; j < 4; j++) o[j] = zero;
    float mi = NEGINF, li = 0.f;

    {   // prologue: stage tile 0 into buf 0
        uint4 k0a = *reinterpret_cast<const uint4*>(&kh[kbase + (size_t)c0row * HEAD_D + ccg * 8]);
        uint4 k0b = *reinterpret_cast<const uint4*>(&kh[kbase + (size_t)(c0row + 32) * HEAD_D + ccg * 8]);
        uint4 v0a = *reinterpret_cast<const uint4*>(&vtg[vbase + (size_t)c0row * T_LEN + ccg * 8]);
        uint4 v0b = *reinterpret_cast<const uint4*>(&vtg[vbase + (size_t)(c0row + 32) * T_LEN + ccg * 8]);
        *reinterpret_cast<uint4*>(&Ks[0][sel0]) = k0a;
        *reinterpret_cast<uint4*>(&Ks[0][sel1]) = k0b;
        *reinterpret_cast<uint4*>(&Vs[0][sel0]) = v0a;
        *reinterpret_cast<uint4*>(&Vs[0][sel1]) = v0b;
    }
    __syncthreads();

    for (int kt = 0; kt < nt; ++kt) {
        const int cur = kt & 1;
        const int kv0 = kt * 64;
        const bool pf = (kt + 1 < nt);
        uint4 kra, krb, vra, vrb;
        if (pf) {   // issue next-tile global loads early (T14)
            const int kn = kv0 + 64;
            kra = *reinterpret_cast<const uint4*>(&kh[kbase + (size_t)(kn + c0row) * HEAD_D + ccg * 8]);
            krb = *reinterpret_cast<const uint4*>(&kh[kbase + (size_t)(kn + c0row + 32) * HEAD_D + ccg * 8]);
            vra = *reinterpret_cast<const uint4*>(&vtg[vbase + (size_t)c0row * T_LEN + kn + ccg * 8]);
            vrb = *reinterpret_cast<const uint4*>(&vtg[vbase + (size_t)(c0row + 32) * T_LEN + kn + ccg * 8]);
        }

        // S^T: lane holds S[k = kv0+j*16+g*4+r][q = qlo+q15]
        f32x4 sT[4];
#pragma unroll
        for (int j = 0; j < 4; j++) sT[j] = zero;
        __builtin_amdgcn_s_setprio(1);
#pragma unroll
        for (int kk = 0; kk < 2; ++kk) {
            const int ko = (kk * 32 + g * 8) ^ ksw;
#pragma unroll
            for (int j = 0; j < 4; j++) {
                bf16x8 bk = *reinterpret_cast<const bf16x8*>(&Ks[cur][(j * 16 + q15) * 64 + ko]);
                sT[j] = __builtin_amdgcn_mfma_f32_16x16x32_bf16(bk, aq[kk], sT[j], 0, 0, 0);
            }
        }
        __builtin_amdgcn_s_setprio(0);
        if (kv0 + 63 > qlo) {   // causal mask
            const int qg = qlo + q15;
#pragma unroll
            for (int j = 0; j < 4; j++)
#pragma unroll
                for (int r = 0; r < 4; r++)
                    if (kv0 + j * 16 + g * 4 + r > qg) sT[j][r] = NEGINF;
        }
        // online softmax in exp2 domain (own-lane stats; q = lane&15)
        float mx = sT[0][0];
#pragma unroll
        for (int j = 0; j < 4; j++)
#pragma unroll
            for (int r = 0; r < 4; r++) mx = fmaxf(mx, sT[j][r]);
        mx = fmaxf(mx, __shfl_xor(mx, 16));
        mx = fmaxf(mx, __shfl_xor(mx, 32));
        const float mnew = fmaxf(mi, mx);
        const float al = __builtin_exp2f(mi - mnew);
        float ps = 0.f;
#pragma unroll
        for (int j = 0; j < 4; j++)
#pragma unroll
            for (int r = 0; r < 4; r++) {
                float p = __builtin_exp2f(sT[j][r] - mnew);
                sT[j][r] = p;
                ps += p;
            }
        ps += __shfl_xor(ps, 16);
        ps += __shfl_xor(ps, 32);
        li = li * al + ps;
        mi = mnew;
        // P -> per-wave Ps LDS (B-frag source for PV)
#pragma unroll
        for (int j = 0; j < 4; j++)
#pragma unroll
            for (int pr = 0; pr < 2; ++pr) {
                bf16x2 pk;
                pk[0] = (bf16)sT[j][2 * pr];
                pk[1] = (bf16)sT[j][2 * pr + 1];
                *reinterpret_cast<bf16x2*>(&Ps[w][q15][j * 16 + g * 4 + 2 * pr]) = pk;
            }
        // rescale O (own-lane alpha)
#pragma unroll
        for (int j = 0; j < 4; j++)
#pragma unroll
            for (int r = 0; r < 4; r++) o[j][r] *= al;
        // O^T += V^T * P^T
        __builtin_amdgcn_s_setprio(1);
#pragma unroll
        for (int kk = 0; kk < 2; ++kk) {
            bf16x8 pb = *reinterpret_cast<const bf16x8*>(&Ps[w][q15][kk * 32 + g * 8]);
            const int ko = (kk * 32 + g * 8) ^ ksw;
#pragma unroll
            for (int j = 0; j < 4; j++) {
                bf16x8 av = *reinterpret_cast<const bf16x8*>(&Vs[cur][(j * 16 + q15) * 64 + ko]);
                o[j] = __builtin_amdgcn_mfma_f32_16x16x32_bf16(av, pb, o[j], 0, 0, 0);
            }
        }
        __builtin_amdgcn_s_setprio(0);
        if (pf) {   // write next tile into the other buffer, one barrier/tile
            *reinterpret_cast<uint4*>(&Ks[cur ^ 1][sel0]) = kra;
            *reinterpret_cast<uint4*>(&Ks[cur ^ 1][sel1]) = krb;
            *reinterpret_cast<uint4*>(&Vs[cur ^ 1][sel0]) = vra;
            *reinterpret_cast<uint4*>(&Vs[cur ^ 1][sel1]) = vrb;
        }
        __syncthreads();
    }

    // epilogue: lane owns q = qlo + q15, d = j*16 + g*4 + r
    const int b = bh >> 4, h = bh & 15;
    const float inv = 1.f / li;
    const int t = qlo + q15;
    bf16* dst = &ao[((size_t)(b * T_LEN + t)) * D_DIM + h * HEAD_D];
#pragma unroll
    for (int j = 0; j < 4; j++) {
        bf16x4 pk;
#pragma unroll
        for (int r = 0; r < 4; r++) pk[r] = (bf16)(o[j][r] * inv);
        *reinterpret_cast<bf16x4*>(&dst[j * 16 + g * 4]) = pk;
    }
}

// --------------------------------------------------------------------------
extern "C" void kernel_launch(void* const* d_in, const int* in_sizes, int n_in,
                              void* d_out, int out_size, void* d_ws, size_t ws_size,
                              hipStream_t stream) {
    const float* x  = (const float*)d_in[0];
    const float* Wq = (const float*)d_in[1];
    const float* Wk = (const float*)d_in[2];
    const float* Wv = (const float*)d_in[3];
    const float* Wo = (const float*)d_in[4];
    const float* fc = (const float*)d_in[5];
    const float* fs = (const float*)d_in[6];
    float* out = (float*)d_out;

    char* ws = (char*)d_ws;
    const size_t MB = 1024 * 1024;
    bf16* xb   = (bf16*)(ws);             // 8 MiB  [4096,1024]
    bf16* wqkv = (bf16*)(ws + 8 * MB);    // 6 MiB  [3072,1024]
    bf16* wob  = (bf16*)(ws + 14 * MB);   // 2 MiB
    bf16* qhd  = (bf16*)(ws + 16 * MB);   // head-major [B,H,T,hd] (unroped)
    bf16* khd  = (bf16*)(ws + 24 * MB);   // head-major [B,H,T,hd] (roped in GEMM)
    bf16* vt   = (bf16*)(ws + 32 * MB);   // head-major transposed [B,H,hd,T]
    bf16* ao   = (bf16*)(ws + 40 * MB);   // row-major [B*T, D]

    prep_cvt<<<2048, 256, 0, stream>>>(x, Wq, Wk, Wv, Wo, xb, wqkv, wob);

    dim3 gq(24, 32);   // fused QKV: N = 3072 (k-rope fused in epilogue)
    gemm_glds<0><<<gq, 256, 0, stream>>>(xb, wqkv, qhd, khd, vt, nullptr, fc, fs);

    attn_fwd<<<1024, 256, 0, stream>>>(qhd, khd, vt, fc, fs, ao);

    dim3 go(8, 32);
    gemm_glds<1><<<go, 256, 0, stream>>>(ao, wob, nullptr, nullptr, nullptr, out, fc, fs);
}

// Round 20
// 101.759 us; speedup vs baseline: 1.0305x; 1.0305x over previous
//
#include <hip/hip_runtime.h>
#include <math.h>

typedef __bf16 bf16;
typedef __bf16 bf16x8 __attribute__((ext_vector_type(8)));
typedef __bf16 bf16x4 __attribute__((ext_vector_type(4)));
typedef __bf16 bf16x2 __attribute__((ext_vector_type(2)));
typedef float  f32x4  __attribute__((ext_vector_type(4)));

#define B_DIM 2
#define T_LEN 2048
#define D_DIM 1024
#define N_HEAD 16
#define HEAD_D 64
#define M_ROWS (B_DIM * T_LEN)  // 4096

#define GLDS16(g, l)                                                          \
    __builtin_amdgcn_global_load_lds(                                         \
        (const __attribute__((address_space(1))) void*)(g),                   \
        (__attribute__((address_space(3))) void*)(l), 16, 0, 0)

// ---------------- fused f32 -> bf16 conversion of x + all weights ---------
// grid-stride x4: 2048 blocks, 4 float4 per thread (ILP for the BW-bound pass)
__global__ void prep_cvt(const float* __restrict__ x, const float* __restrict__ wq,
                         const float* __restrict__ wk, const float* __restrict__ wv,
                         const float* __restrict__ wo, bf16* __restrict__ xb,
                         bf16* __restrict__ wqkv, bf16* __restrict__ wob) {
    const int id0 = blockIdx.x * blockDim.x + threadIdx.x;   // 0..524287
#pragma unroll
    for (int u = 0; u < 4; ++u) {
        int id = id0 + u * (1 << 19);                         // float4 units
        const float* src; bf16* dst; int off;
        if (id < (1 << 20)) { src = x; dst = xb; off = id; }
        else {
            int r = id - (1 << 20);
            int wi = r >> 18;
            off = r & ((1 << 18) - 1);
            src = wi == 0 ? wq : wi == 1 ? wk : wi == 2 ? wv : wo;
            dst = wi < 3 ? wqkv + ((size_t)wi << 20) : wob;
        }
        float4 v = reinterpret_cast<const float4*>(src)[off];
        bf16x4 w;
        w[0] = (bf16)v.x; w[1] = (bf16)v.y; w[2] = (bf16)v.z; w[3] = (bf16)v.w;
        reinterpret_cast<bf16x4*>(dst)[off] = w;
    }
}

// ---------------- GEMM: C = A[M,K] * Bm[N,K]^T ----------------------------
// m97 structure: single-buffered 32KB LDS, global_load_lds w16, src-side XOR
// swizzle, (256,4) — measured best; (256,5) was neutral-to-worse (R17).
// MODE 0: N=3072 fused QKV -> q plain head-major [B,H,T,hd];
// k head-major WITH ROPE fused in epilogue; v transposed [B,H,hd,T].
// MODE 1: N=1024 -> f32 row-major [M,N].
template <int MODE>
__global__ __launch_bounds__(256, 4)
void gemm_glds(const bf16* __restrict__ A, const bf16* __restrict__ Bm,
               bf16* __restrict__ q, bf16* __restrict__ k, bf16* __restrict__ v,
               float* __restrict__ outf, const float* __restrict__ fc,
               const float* __restrict__ fs) {
    constexpr int K = D_DIM;
    __shared__ bf16 As[128 * 64];
    __shared__ bf16 Bs[128 * 64];
    const int tid = threadIdx.x, lane = tid & 63, wave = tid >> 6;
    const int wr = wave >> 1, wc = wave & 1;
    const int rowg = lane >> 4, col0 = lane & 15;

    const int nwg = gridDim.x * gridDim.y, cpx = nwg >> 3;
    const int lin = blockIdx.x + blockIdx.y * gridDim.x;
    const int nid = (lin & 7) * cpx + (lin >> 3);
    const int bx = nid % gridDim.x, by = nid / gridDim.x;
    const int m0 = by * 128, n0 = bx * 128;

    const int srow = lane >> 3;
    const int schk = (lane & 7) ^ srow;
    const bf16* gA = A + (size_t)(m0 + wave * 32 + srow) * K + schk * 8;
    const bf16* gB = Bm + (size_t)(n0 + wave * 32 + srow) * K + schk * 8;

    f32x4 acc[4][4];
    f32x4 zero = {0.f, 0.f, 0.f, 0.f};
#pragma unroll
    for (int i = 0; i < 4; i++)
#pragma unroll
        for (int j = 0; j < 4; j++) acc[i][j] = zero;

#pragma unroll 1
    for (int kt = 0; kt < 16; ++kt) {
        const int k0 = kt * 64;
#pragma unroll
        for (int t = 0; t < 4; ++t) {
            GLDS16(gA + k0 + t * 8 * K, &As[(wave * 32 + t * 8) * 64]);
            GLDS16(gB + k0 + t * 8 * K, &Bs[(wave * 32 + t * 8) * 64]);
        }
        __syncthreads();
#pragma unroll
        for (int kk = 0; kk < 2; ++kk) {
            bf16x8 af[4], bfr[4];
#pragma unroll
            for (int i = 0; i < 4; i++) {
                int R = wr * 64 + i * 16 + col0;
                af[i] = *reinterpret_cast<const bf16x8*>(&As[R * 64 + (((kk * 4 + rowg) ^ (R & 7)) * 8)]);
            }
#pragma unroll
            for (int j = 0; j < 4; j++) {
                int R = wc * 64 + j * 16 + col0;
                bfr[j] = *reinterpret_cast<const bf16x8*>(&Bs[R * 64 + (((kk * 4 + rowg) ^ (R & 7)) * 8)]);
            }
#pragma unroll
            for (int i = 0; i < 4; i++)
#pragma unroll
                for (int j = 0; j < 4; j++)
                    acc[i][j] = __builtin_amdgcn_mfma_f32_16x16x32_bf16(af[i], bfr[j], acc[i][j], 0, 0, 0);
        }
        __syncthreads();
    }

    if constexpr (MODE == 0) {
        const int which = bx >> 3;                    // 0=q, 1=k, 2=v
        if (which == 0) {                             // q: plain (attn ropes it)
#pragma unroll
            for (int i = 0; i < 4; i++)
#pragma unroll
                for (int j = 0; j < 4; j++)
#pragma unroll
                    for (int r = 0; r < 4; r++) {
                        int m = m0 + wr * 64 + i * 16 + rowg * 4 + r;
                        int n = (n0 + wc * 64 + j * 16 + col0) & 1023;
                        int b = m >> 11, t = m & 2047, h = n >> 6, d = n & 63;
                        q[(((size_t)(b * N_HEAD + h)) * T_LEN + t) * HEAD_D + d] = (bf16)acc[i][j][r];
                    }
        } else if (which == 1) {                      // k: rope fused (verified R10/R11)
            const float sgnf = (col0 & 1) ? 1.f : -1.f;
#pragma unroll
            for (int i = 0; i < 4; i++)
#pragma unroll
                for (int j = 0; j < 4; j++) {
                    int nn = (n0 + wc * 64 + j * 16 + col0) & 1023;
                    int h = nn >> 6, d = nn & 63, i2 = d >> 1;
#pragma unroll
                    for (int r = 0; r < 4; r++) {
                        int m = m0 + wr * 64 + i * 16 + rowg * 4 + r;
                        int b = m >> 11, t = m & 2047;
                        float own = acc[i][j][r];
                        float part = __shfl_xor(own, 1);
                        float c = fc[t * 32 + i2], s = fs[t * 32 + i2];
                        float res = own * c + part * (sgnf * s);   // rope pair
                        k[(((size_t)(b * N_HEAD + h)) * T_LEN + t) * HEAD_D + d] = (bf16)res;
                    }
                }
        } else {                                      // v: transposed
#pragma unroll
            for (int i = 0; i < 4; i++)
#pragma unroll
                for (int j = 0; j < 4; j++) {
                    bf16x4 pk;
#pragma unroll
                    for (int r = 0; r < 4; r++) pk[r] = (bf16)acc[i][j][r];
                    int m = m0 + wr * 64 + i * 16 + rowg * 4;
                    int n = (n0 + wc * 64 + j * 16 + col0) & 1023;
                    int b = m >> 11, t = m & 2047, h = n >> 6, d = n & 63;
                    *reinterpret_cast<bf16x4*>(
                        &v[(((size_t)(b * N_HEAD + h)) * HEAD_D + d) * T_LEN + t]) = pk;
                }
        }
    } else {
#pragma unroll
        for (int i = 0; i < 4; i++)
#pragma unroll
            for (int j = 0; j < 4; j++)
#pragma unroll
                for (int r = 0; r < 4; r++) {
                    int m = m0 + wr * 64 + i * 16 + rowg * 4 + r;
                    int n = n0 + wc * 64 + j * 16 + col0;
                    outf[(size_t)m * D_DIM + n] = acc[i][j][r];
                }
    }
}

// ---------------- rope helper: 8 bf16 = 4 (even,odd) pairs ----------------
__device__ inline bf16x8 rope8(bf16x8 v, f32x4 c4, f32x4 s4, float scale) {
    bf16x8 r;
#pragma unroll
    for (int m = 0; m < 4; ++m) {
        float a = (float)v[2 * m], b = (float)v[2 * m + 1];
        r[2 * m]     = (bf16)((a * c4[m] - b * s4[m]) * scale);
        r[2 * m + 1] = (bf16)((a * s4[m] + b * c4[m]) * scale);
    }
    return r;
}

// ---------------- causal flash attention (R12/R16/R18 config — FINAL) -----
// 4 waves x 16 q-rows = QBLK 64; KVBLK 64; double-buffered K/V LDS, one
// __syncthreads per tile, T14 reg-prefetch. Grid 1024, qi = 31 - (idx>>2)
// descending (LPT). bh pinned per XCD. Swapped QK^T and swapped PV
// (q = lane&15 everywhere). In-kernel Q-rope (+0.125); __expf softmax
// (fast OCML intrinsic: v_mul+v_exp — builtin exp2f was SLOWER, +3.8µs);
// unconditional rescale; padded Ps[16][72]. All tested perturbations
// regressed: shfl-P (+13µs), swizzled Ps (+1.4), VGPR squeeze (+5.6),
// V-from-global (+42), GEMM (256,5) (+2.3), builtin-exp2 (+3.8).
__global__ __launch_bounds__(256, 3)
void attn_fwd(const bf16* __restrict__ qh, const bf16* __restrict__ kh,
              const bf16* __restrict__ vtg, const float* __restrict__ fc,
              const float* __restrict__ fs, bf16* __restrict__ ao) {
    __shared__ __align__(16) bf16 Ks[2][64 * 64];
    __shared__ __align__(16) bf16 Vs[2][64 * 64];
    __shared__ __align__(16) bf16 Ps[4][16][72];
    const int tid = threadIdx.x, lane = tid & 63, w = tid >> 6;
    const int g = lane >> 4, q15 = lane & 15;
    const int lin = blockIdx.x;                       // grid 1024
    const int xcd = lin & 7, idx = lin >> 3;
    const int qi = 31 - (idx >> 2);                   // descending -> LPT
    const int bh = xcd * 4 + (idx & 3);
    const size_t kbase = (size_t)bh * T_LEN * HEAD_D;   // [t][d]
    const size_t vbase = (size_t)bh * HEAD_D * T_LEN;   // [d][t]
    // staging: 256 threads x 2 rows per matrix (rows r and r+32)
    const int c0row = tid >> 3, ccg = tid & 7;
    const int swz = (ccg * 8) ^ ((c0row & 7) * 8);    // (c0row+32)&7 == c0row&7
    const int sel0 = c0row * 64 + swz;
    const int sel1 = sel0 + 32 * 64;
    const int ksw = (q15 & 7) * 8;

    const float NEGINF = -__builtin_inff();
    f32x4 zero = {0.f, 0.f, 0.f, 0.f};

    const int nt = qi + 1;
    const int qlo = qi * 64 + w * 16;

    // Q fragments: load, rope in-register, fold 1/8 scale
    bf16x8 aq[2];
#pragma unroll
    for (int kk = 0; kk < 2; ++kk) {
        bf16x8 qv = *reinterpret_cast<const bf16x8*>(
            &qh[kbase + (size_t)(qlo + q15) * HEAD_D + kk * 32 + g * 8]);
        f32x4 c4 = *reinterpret_cast<const f32x4*>(&fc[(qlo + q15) * 32 + kk * 16 + g * 4]);
        f32x4 s4 = *reinterpret_cast<const f32x4*>(&fs[(qlo + q15) * 32 + kk * 16 + g * 4]);
        aq[kk] = rope8(qv, c4, s4, 0.125f);
    }

    f32x4 o[4];
#pragma unroll
    for (int j = 0; j < 4; j++) o[j] = zero;
    float mi = NEGINF, li = 0.f;

    {   // prologue: stage tile 0 into buf 0
        uint4 k0a = *reinterpret_cast<const uint4*>(&kh[kbase + (size_t)c0row * HEAD_D + ccg * 8]);
        uint4 k0b = *reinterpret_cast<const uint4*>(&kh[kbase + (size_t)(c0row + 32) * HEAD_D + ccg * 8]);
        uint4 v0a = *reinterpret_cast<const uint4*>(&vtg[vbase + (size_t)c0row * T_LEN + ccg * 8]);
        uint4 v0b = *reinterpret_cast<const uint4*>(&vtg[vbase + (size_t)(c0row + 32) * T_LEN + ccg * 8]);
        *reinterpret_cast<uint4*>(&Ks[0][sel0]) = k0a;
        *reinterpret_cast<uint4*>(&Ks[0][sel1]) = k0b;
        *reinterpret_cast<uint4*>(&Vs[0][sel0]) = v0a;
        *reinterpret_cast<uint4*>(&Vs[0][sel1]) = v0b;
    }
    __syncthreads();

    for (int kt = 0; kt < nt; ++kt) {
        const int cur = kt & 1;
        const int kv0 = kt * 64;
        const bool pf = (kt + 1 < nt);
        uint4 kra, krb, vra, vrb;
        if (pf) {   // issue next-tile global loads early (T14)
            const int kn = kv0 + 64;
            kra = *reinterpret_cast<const uint4*>(&kh[kbase + (size_t)(kn + c0row) * HEAD_D + ccg * 8]);
            krb = *reinterpret_cast<const uint4*>(&kh[kbase + (size_t)(kn + c0row + 32) * HEAD_D + ccg * 8]);
            vra = *reinterpret_cast<const uint4*>(&vtg[vbase + (size_t)c0row * T_LEN + kn + ccg * 8]);
            vrb = *reinterpret_cast<const uint4*>(&vtg[vbase + (size_t)(c0row + 32) * T_LEN + kn + ccg * 8]);
        }

        // S^T: lane holds S[k = kv0+j*16+g*4+r][q = qlo+q15]
        f32x4 sT[4];
#pragma unroll
        for (int j = 0; j < 4; j++) sT[j] = zero;
        __builtin_amdgcn_s_setprio(1);
#pragma unroll
        for (int kk = 0; kk < 2; ++kk) {
            const int ko = (kk * 32 + g * 8) ^ ksw;
#pragma unroll
            for (int j = 0; j < 4; j++) {
                bf16x8 bk = *reinterpret_cast<const bf16x8*>(&Ks[cur][(j * 16 + q15) * 64 + ko]);
                sT[j] = __builtin_amdgcn_mfma_f32_16x16x32_bf16(bk, aq[kk], sT[j], 0, 0, 0);
            }
        }
        __builtin_amdgcn_s_setprio(0);
        if (kv0 + 63 > qlo) {   // causal mask
            const int qg = qlo + q15;
#pragma unroll
            for (int j = 0; j < 4; j++)
#pragma unroll
                for (int r = 0; r < 4; r++)
                    if (kv0 + j * 16 + g * 4 + r > qg) sT[j][r] = NEGINF;
        }
        // online softmax (own-lane stats; q = lane&15)
        float mx = sT[0][0];
#pragma unroll
        for (int j = 0; j < 4; j++)
#pragma unroll
            for (int r = 0; r < 4; r++) mx = fmaxf(mx, sT[j][r]);
        mx = fmaxf(mx, __shfl_xor(mx, 16));
        mx = fmaxf(mx, __shfl_xor(mx, 32));
        const float mnew = fmaxf(mi, mx);
        const float al = __expf(mi - mnew);
        float ps = 0.f;
#pragma unroll
        for (int j = 0; j < 4; j++)
#pragma unroll
            for (int r = 0; r < 4; r++) {
                float p = __expf(sT[j][r] - mnew);
                sT[j][r] = p;
                ps += p;
            }
        ps += __shfl_xor(ps, 16);
        ps += __shfl_xor(ps, 32);
        li = li * al + ps;
        mi = mnew;
        // P -> per-wave Ps LDS (B-frag source for PV)
#pragma unroll
        for (int j = 0; j < 4; j++)
#pragma unroll
            for (int pr = 0; pr < 2; ++pr) {
                bf16x2 pk;
                pk[0] = (bf16)sT[j][2 * pr];
                pk[1] = (bf16)sT[j][2 * pr + 1];
                *reinterpret_cast<bf16x2*>(&Ps[w][q15][j * 16 + g * 4 + 2 * pr]) = pk;
            }
        // rescale O (own-lane alpha)
#pragma unroll
        for (int j = 0; j < 4; j++)
#pragma unroll
            for (int r = 0; r < 4; r++) o[j][r] *= al;
        // O^T += V^T * P^T
        __builtin_amdgcn_s_setprio(1);
#pragma unroll
        for (int kk = 0; kk < 2; ++kk) {
            bf16x8 pb = *reinterpret_cast<const bf16x8*>(&Ps[w][q15][kk * 32 + g * 8]);
            const int ko = (kk * 32 + g * 8) ^ ksw;
#pragma unroll
            for (int j = 0; j < 4; j++) {
                bf16x8 av = *reinterpret_cast<const bf16x8*>(&Vs[cur][(j * 16 + q15) * 64 + ko]);
                o[j] = __builtin_amdgcn_mfma_f32_16x16x32_bf16(av, pb, o[j], 0, 0, 0);
            }
        }
        __builtin_amdgcn_s_setprio(0);
        if (pf) {   // write next tile into the other buffer, one barrier/tile
            *reinterpret_cast<uint4*>(&Ks[cur ^ 1][sel0]) = kra;
            *reinterpret_cast<uint4*>(&Ks[cur ^ 1][sel1]) = krb;
            *reinterpret_cast<uint4*>(&Vs[cur ^ 1][sel0]) = vra;
            *reinterpret_cast<uint4*>(&Vs[cur ^ 1][sel1]) = vrb;
        }
        __syncthreads();
    }

    // epilogue: lane owns q = qlo + q15, d = j*16 + g*4 + r
    const int b = bh >> 4, h = bh & 15;
    const float inv = 1.f / li;
    const int t = qlo + q15;
    bf16* dst = &ao[((size_t)(b * T_LEN + t)) * D_DIM + h * HEAD_D];
#pragma unroll
    for (int j = 0; j < 4; j++) {
        bf16x4 pk;
#pragma unroll
        for (int r = 0; r < 4; r++) pk[r] = (bf16)(o[j][r] * inv);
        *reinterpret_cast<bf16x4*>(&dst[j * 16 + g * 4]) = pk;
    }
}

// --------------------------------------------------------------------------
extern "C" void kernel_launch(void* const* d_in, const int* in_sizes, int n_in,
                              void* d_out, int out_size, void* d_ws, size_t ws_size,
                              hipStream_t stream) {
    const float* x  = (const float*)d_in[0];
    const float* Wq = (const float*)d_in[1];
    const float* Wk = (const float*)d_in[2];
    const float* Wv = (const float*)d_in[3];
    const float* Wo = (const float*)d_in[4];
    const float* fc = (const float*)d_in[5];
    const float* fs = (const float*)d_in[6];
    float* out = (float*)d_out;

    char* ws = (char*)d_ws;
    const size_t MB = 1024 * 1024;
    bf16* xb   = (bf16*)(ws);             // 8 MiB  [4096,1024]
    bf16* wqkv = (bf16*)(ws + 8 * MB);    // 6 MiB  [3072,1024]
    bf16* wob  = (bf16*)(ws + 14 * MB);   // 2 MiB
    bf16* qhd  = (bf16*)(ws + 16 * MB);   // head-major [B,H,T,hd] (unroped)
    bf16* khd  = (bf16*)(ws + 24 * MB);   // head-major [B,H,T,hd] (roped in GEMM)
    bf16* vt   = (bf16*)(ws + 32 * MB);   // head-major transposed [B,H,hd,T]
    bf16* ao   = (bf16*)(ws + 40 * MB);   // row-major [B*T, D]

    prep_cvt<<<2048, 256, 0, stream>>>(x, Wq, Wk, Wv, Wo, xb, wqkv, wob);

    dim3 gq(24, 32);   // fused QKV: N = 3072 (k-rope fused in epilogue)
    gemm_glds<0><<<gq, 256, 0, stream>>>(xb, wqkv, qhd, khd, vt, nullptr, fc, fs);

    attn_fwd<<<1024, 256, 0, stream>>>(qhd, khd, vt, fc, fs, ao);

    dim3 go(8, 32);
    gemm_glds<1><<<go, 256, 0, stream>>>(ao, wob, nullptr, nullptr, nullptr, out, fc, fs);
}